// Round 4
// baseline (129.840 us; speedup 1.0000x reference)
//
#include <hip/hip_runtime.h>
#include <hip/hip_bf16.h>

typedef unsigned short u16;
typedef unsigned int u32;
typedef __attribute__((ext_vector_type(8))) __bf16 bf16x8;
typedef __attribute__((ext_vector_type(4))) float f32x4;

#define NB 4       // batch
#define SQ 4096    // seq len
#define DM 1024    // d_model
#define RPC 4096   // rows per residue class (NB*SQ/4)
#define S4 (4 * DM)

#define VMCNT(n) asm volatile("s_waitcnt vmcnt(" #n ")" ::: "memory")
#define LGKM0()  asm volatile("s_waitcnt lgkmcnt(0)" ::: "memory")
#define BARRIER() asm volatile("s_barrier" ::: "memory")

__device__ __forceinline__ u16 f2b(float f) {
  u32 u = __builtin_bit_cast(u32, f);
  u32 r = u + 0x7fffu + ((u >> 16) & 1u);
  return (u16)(r >> 16);
}
__device__ __forceinline__ u32 cvt2(float lo, float hi) {
  u16 a = __builtin_bit_cast(u16, __float2bfloat16(lo));
  u16 b = __builtin_bit_cast(u16, __float2bfloat16(hi));
  return (u32)a | ((u32)b << 16);
}
__device__ __forceinline__ float dot2(u32 q, u32 k) {
  float ql = __builtin_bit_cast(float, q << 16);
  float qh = __builtin_bit_cast(float, q & 0xffff0000u);
  float kl = __builtin_bit_cast(float, k << 16);
  float kh = __builtin_bit_cast(float, k & 0xffff0000u);
  return ql * kl + qh * kh;
}
__device__ __forceinline__ u32 mul2(u32 v, float p) {
  float lo = __builtin_bit_cast(float, v << 16) * p;
  float hi = __builtin_bit_cast(float, v & 0xffff0000u) * p;
  return (u32)f2b(lo) | ((u32)f2b(hi) << 16);
}
__device__ __forceinline__ void gll16(const void* g, void* l) {
  __builtin_amdgcn_global_load_lds(
      (const __attribute__((address_space(1))) void*)g,
      (__attribute__((address_space(3))) void*)l, 16, 0, 0);
}

// ---- pack W{q,k,v} for class c into swizzled LDS-image tiles ----
// B^T panel per class: [768 N][1024 K]; tiles BN=192 x BK=64.
// u16 idx = ((c*4+n0)*16 + k64)*12288 + nrow*64 + ((u ^ (nrow&7))<<3) + e
__global__ __launch_bounds__(256) void trans_qkv(const float* __restrict__ Wq,
                                                 const float* __restrict__ Wk,
                                                 const float* __restrict__ Wv,
                                                 u16* __restrict__ WTp) {
  __shared__ float T[64][65];
  const int k0 = blockIdx.x * 64, j0 = blockIdx.y * 64, c = blockIdx.z;
  const int msel = j0 >> 8;
  const float* W = (msel == 0) ? Wq : ((msel == 1) ? Wk : Wv);
  const int slot = (j0 & 255) >> 6;
  const int colbase = (c + 4 * slot) * 64;
  const int tid = threadIdx.x;
  const int rr = tid >> 6, cc = tid & 63;
#pragma unroll
  for (int it = 0; it < 16; ++it) {
    const int kk = rr + it * 4;
    T[kk][cc] = W[(size_t)(k0 + kk) * 1024 + colbase + cc];
  }
  __syncthreads();
  const int k64 = k0 >> 6;
  const int u = cc >> 3, e = cc & 7;
#pragma unroll
  for (int it = 0; it < 16; ++it) {
    const int jj = rr + it * 4;
    const int j = j0 + jj;
    const int n0 = j / 192, nrow = j - n0 * 192;
    WTp[((size_t)((c * 4 + n0) * 16 + k64)) * 12288 + nrow * 64 + (((u ^ (nrow & 7))) << 3) + e] =
        f2b(T[cc][jj]);
  }
}

// ---- pack Wo for class c: B^T [1024 N][256 K], tiles BN=256 x BK=64 ----
__global__ __launch_bounds__(256) void trans_wo(const float* __restrict__ Wo,
                                                u16* __restrict__ WoTp) {
  __shared__ float T[64][65];
  const int j0 = blockIdx.x * 64, e0 = blockIdx.y * 64, c = blockIdx.z;
  const int rowbase = c * 64 + (j0 >> 6) * 256;
  const int tid = threadIdx.x;
  const int rr = tid >> 6, cc = tid & 63;
#pragma unroll
  for (int it = 0; it < 16; ++it) {
    const int jj = rr + it * 4;
    T[jj][cc] = Wo[(size_t)(rowbase + jj) * 1024 + e0 + cc];
  }
  __syncthreads();
  const int k64 = j0 >> 6;
  const int u = cc >> 3, e = cc & 7;
#pragma unroll
  for (int it = 0; it < 16; ++it) {
    const int ee = rr + it * 4;
    const int n = e0 + ee;
    const int n0 = n >> 8, nrow = n & 255;
    WoTp[((size_t)((c * 4 + n0) * 4 + k64)) * 16384 + nrow * 64 + (((u ^ (nrow & 7))) << 3) + e] =
        f2b(T[cc][ee]);
  }
}

__global__ __launch_bounds__(256) void bias_pack(const float* __restrict__ bq,
                                                 const float* __restrict__ bk,
                                                 const float* __restrict__ bv,
                                                 float* __restrict__ biasp) {
  const int idx = blockIdx.x * 256 + threadIdx.x;  // 4*768
  if (idx >= 3072) return;
  const int c = idx / 768, j = idx % 768;
  const int msel = j >> 8, jj = j & 255;
  const int col = (c + 4 * (jj >> 6)) * 64 + (jj & 63);
  const float* bb = (msel == 0) ? bq : ((msel == 1) ? bk : bv);
  biasp[idx] = bb[col];
}

// ---- GEMM1: per class, [4096 x 768] = x_rows(c)[4096 x 1024] @ WTp^T ----
// BM=256, BN=192, BK=64; 8 waves (4Mx2N), wave tile 64x96.
// Interleaved schedule: {read A-frags, lgkm0, barrier} then
// {LOADA(t+3) | gll B(t+2)->tri | MFMA kk0 | dswrite A(t+2) | MFMA kk1 | vmcnt(11)}.
__global__ __launch_bounds__(512, 2) void gemm_qkv(const float* __restrict__ x,
                                                   const u16* __restrict__ WTp,
                                                   const float* __restrict__ biasp,
                                                   u16* __restrict__ QKV) {
  __shared__ __align__(16) u16 As2[2 * 16384];  // A: 2 x (256x64) swizzled
  __shared__ __align__(16) u16 Bs3[3 * 12288];  // B: 3 x (192x64) swizzled
  const int p = blockIdx.x;
  const int L = (p & 7) * 32 + (p >> 3);  // XCD-contiguous logical id
  const int c = L >> 6, rem = L & 63;
  const int m0 = rem >> 2, n0 = rem & 3;
  const int tid = threadIdx.x;
  const int lane = tid & 63, w = tid >> 6;
  const int wm = w >> 1, wn = w & 1;
  const int l15 = lane & 15, l16 = lane >> 4;

  const int rbase = m0 * 256;
  const int b = rbase >> 10;
  const int sbase = ((rbase & 1023) << 2) + c;
  const float* xA = x + (size_t)(b * SQ + sbase) * DM;  // row stride S4

  // A staging: thread handles rows (tid>>3)+64j, cols (tid&7)*8..+7
  const int aw0 = ((tid >> 3) * 64) + ((((tid & 7) ^ ((tid >> 3) & 7))) << 3);
  const float* aptr = xA + (size_t)(tid >> 3) * S4 + (tid & 7) * 8;
  const u16* Bsrc = WTp + (size_t)((c * 4 + n0) * 16) * 12288;

  f32x4 acc[4][6];
#pragma unroll
  for (int i = 0; i < 4; ++i)
#pragma unroll
    for (int j = 0; j < 6; ++j) acc[i][j] = (f32x4){0.f, 0.f, 0.f, 0.f};

  // frag bases: row&7 == l15&7 for all frags (strides mult of 8 rows)
  int abase[2], bbase[2];
#pragma unroll
  for (int kk = 0; kk < 2; ++kk) {
    const int unit = kk * 4 + l16;
    abase[kk] = (wm * 64 + l15) * 64 + ((unit ^ (l15 & 7)) << 3);
    bbase[kk] = (wn * 96 + l15) * 64 + ((unit ^ (l15 & 7)) << 3);
  }

  float4 av0[8], av1[8];

#define LOADA(kt, AV)                                                      \
  {                                                                        \
    _Pragma("unroll") for (int j = 0; j < 4; ++j) {                        \
      const float* s = aptr + (size_t)j * (64 * S4) + (kt) * 64;           \
      AV[2 * j] = *reinterpret_cast<const float4*>(s);                     \
      AV[2 * j + 1] = *reinterpret_cast<const float4*>(s + 4);             \
    }                                                                      \
  }
#define DSWRITE(AV, bufLit)                                                \
  {                                                                        \
    _Pragma("unroll") for (int j = 0; j < 4; ++j) {                        \
      uint4 pk;                                                            \
      pk.x = cvt2(AV[2 * j].x, AV[2 * j].y);                               \
      pk.y = cvt2(AV[2 * j].z, AV[2 * j].w);                               \
      pk.z = cvt2(AV[2 * j + 1].x, AV[2 * j + 1].y);                       \
      pk.w = cvt2(AV[2 * j + 1].z, AV[2 * j + 1].w);                       \
      *reinterpret_cast<uint4*>(&As2[(bufLit) * 16384 + aw0 + j * 4096]) = pk; \
    }                                                                      \
  }
#define ISSUE_B(kt)                                                        \
  {                                                                        \
    const int dst3 = (kt) % 3;                                             \
    _Pragma("unroll") for (int i = 0; i < 3; ++i)                          \
        gll16(Bsrc + (size_t)(kt) * 12288 + tid * 8 + i * 4096,            \
              (char*)Bs3 + dst3 * 24576 + tid * 16 + i * 8192);            \
  }
#define READ_A(Ab, AF0, AF1)                                               \
  {                                                                        \
    _Pragma("unroll") for (int mf = 0; mf < 4; ++mf) {                     \
      AF0[mf] = *reinterpret_cast<const bf16x8*>((Ab) + abase[0] + mf * 1024); \
      AF1[mf] = *reinterpret_cast<const bf16x8*>((Ab) + abase[1] + mf * 1024); \
    }                                                                      \
  }
#define MFMA_CL(AF, kk)                                                    \
  {                                                                        \
    bf16x8 bv[6];                                                          \
    _Pragma("unroll") for (int nf = 0; nf < 6; ++nf)                       \
        bv[nf] = *reinterpret_cast<const bf16x8*>(Bb + bbase[kk] + nf * 1024); \
    __builtin_amdgcn_s_setprio(1);                                         \
    _Pragma("unroll") for (int mf = 0; mf < 4; ++mf)                       \
        _Pragma("unroll") for (int nf = 0; nf < 6; ++nf)                   \
            acc[mf][nf] = __builtin_amdgcn_mfma_f32_16x16x32_bf16(          \
                AF[mf], bv[nf], acc[mf][nf], 0, 0, 0);                     \
    __builtin_amdgcn_s_setprio(0);                                         \
  }

  // ---- prologue: A(0),A(1) staged; B(0),B(1) issued; A(2) in flight ----
  LOADA(0, av0);
  LOADA(1, av1);
  ISSUE_B(0);
  ISSUE_B(1);
  DSWRITE(av0, 0);
  DSWRITE(av1, 1);
  LOADA(2, av0);
  VMCNT(8);  // B(0),B(1) done; A(2) in flight
  LGKM0();
  BARRIER();

#pragma unroll 1
  for (int tp = 0; tp < 8; ++tp) {
    // ===== phase A: t = 2*tp (even): A-buf 0, av-load->av1, dswrite av0 =====
    {
      const int t = 2 * tp;
      const u16* Ab = As2;  // buf 0
      const u16* Bb = Bs3 + (t % 3) * 12288;
      bf16x8 af0[4], af1[4];
      READ_A(Ab, af0, af1);
      LGKM0();
      BARRIER();
      if (t <= 12) LOADA(t + 3, av1);
      if (t <= 13) ISSUE_B(t + 2);
      MFMA_CL(af0, 0);
      if (t <= 13) DSWRITE(av0, 0);  // A(t+2) -> buf 0
      MFMA_CL(af1, 1);
      LGKM0();
      if (t < 14) { VMCNT(11); } else { VMCNT(0); }
      BARRIER();
    }
    // ===== phase B: t = 2*tp+1 (odd): A-buf 1, av-load->av0, dswrite av1 =====
    {
      const int t = 2 * tp + 1;
      const u16* Ab = As2 + 16384;  // buf 1
      const u16* Bb = Bs3 + (t % 3) * 12288;
      bf16x8 af0[4], af1[4];
      READ_A(Ab, af0, af1);
      LGKM0();
      BARRIER();
      if (t <= 12) LOADA(t + 3, av0);
      if (t <= 13) ISSUE_B(t + 2);
      MFMA_CL(af0, 0);
      if (t <= 13) DSWRITE(av1, 1);  // A(t+2) -> buf 1
      MFMA_CL(af1, 1);
      if (t < 15) {
        LGKM0();
        VMCNT(11);
        BARRIER();
      }
    }
  }

  // ---- epilogue: bias + bf16 store ----
  u16* outc = QKV + (size_t)c * RPC * 768;
#pragma unroll
  for (int mf = 0; mf < 4; ++mf) {
#pragma unroll
    for (int nf = 0; nf < 6; ++nf) {
      const int gcol = n0 * 192 + wn * 96 + nf * 16 + l15;
      const float bias = biasp[c * 768 + gcol];
#pragma unroll
      for (int jj = 0; jj < 4; ++jj) {
        const int rowt = wm * 64 + mf * 16 + l16 * 4 + jj;
        outc[(size_t)(rbase + rowt) * 768 + gcol] = f2b(acc[mf][nf][jj] + bias);
      }
    }
  }
#undef LOADA
#undef DSWRITE
#undef ISSUE_B
#undef READ_A
#undef MFMA_CL
}

// ---- attention: per (c,b,segment,half): diagonal scores + softmax + p*V ----
__global__ __launch_bounds__(256) void attn_k(const u16* __restrict__ QKV,
                                              u16* __restrict__ attnYp) {
  __shared__ float sc[4][128];
  const int blk = blockIdx.x;  // 256
  const int c = blk >> 6, b = (blk >> 4) & 3, n = (blk >> 1) & 7, half = blk & 1;
  const int r0 = b * 1024 + n * 128;
  const int m0 = r0 >> 8;
  const int rb = r0 & 255;
  const u16* base = QKV + ((size_t)c * RPC + r0) * 768;
  const int tid = threadIdx.x;
#pragma unroll
  for (int it = 0; it < 2; ++it) {
    const int tt = tid + it * 256;
    const int t = tt & 127, slot = tt >> 7;
    const u16* q = base + (size_t)t * 768 + slot * 64;
    float s = 0.f;
#pragma unroll
    for (int dd = 0; dd < 8; ++dd) {
      uint4 qa = *reinterpret_cast<const uint4*>(q + dd * 8);
      uint4 ka = *reinterpret_cast<const uint4*>(q + 256 + dd * 8);
      s += dot2(qa.x, ka.x) + dot2(qa.y, ka.y) + dot2(qa.z, ka.z) + dot2(qa.w, ka.w);
    }
    sc[slot][t] = s * 0.125f;
  }
  __syncthreads();
  const int w = tid >> 6, lane = tid & 63;
  float v0 = sc[w][lane], v1 = sc[w][lane + 64];
  float m = fmaxf(v0, v1);
#pragma unroll
  for (int off = 32; off; off >>= 1) m = fmaxf(m, __shfl_xor(m, off));
  float e0 = __expf(v0 - m), e1 = __expf(v1 - m);
  float ssum = e0 + e1;
#pragma unroll
  for (int off = 32; off; off >>= 1) ssum += __shfl_xor(ssum, off);
  const float inv = 1.f / ssum;
  sc[w][lane] = e0 * inv;
  sc[w][lane + 64] = e1 * inv;
  __syncthreads();
  u16* yout = attnYp + (size_t)((c * 16 + m0) * 4) * 16384;
#pragma unroll
  for (int it = 0; it < 8; ++it) {
    const int vi = tid + it * 256;
    const int t = vi >> 4, c8 = (vi & 15) + half * 16;
    const float pr = sc[c8 >> 3][t];
    uint4 va = *reinterpret_cast<const uint4*>(base + (size_t)t * 768 + 512 + c8 * 8);
    uint4 ra;
    ra.x = mul2(va.x, pr); ra.y = mul2(va.y, pr); ra.z = mul2(va.z, pr); ra.w = mul2(va.w, pr);
    const int rloc = rb + t;
    const int k64 = c8 >> 3, uu = c8 & 7, pp = uu ^ (rloc & 7);
    *reinterpret_cast<uint4*>(yout + k64 * 16384 + rloc * 64 + pp * 8) = ra;
  }
}

// ---- GEMM2: per class, out_rows(c)[4096 x 1024] = attnY[4096 x 256] @ Wo ----
__global__ __launch_bounds__(512, 2) void gemm_out(const u16* __restrict__ attnYp,
                                                   const u16* __restrict__ WoTp,
                                                   const float* __restrict__ bo,
                                                   float* __restrict__ out) {
  __shared__ __align__(16) u16 As[2][16384];
  __shared__ __align__(16) u16 Bs[2][16384];
  const int p = blockIdx.x;
  const int L = (p & 7) * 32 + (p >> 3);
  const int c = L >> 6, rem = L & 63;
  const int m0 = rem >> 2, n0 = rem & 3;
  const int tid = threadIdx.x;
  const int lane = tid & 63, w = tid >> 6;
  const int wm = w >> 1, wn = w & 1;
  const int l15 = lane & 15, l16 = lane >> 4;

  const u16* Asrc = attnYp + (size_t)((c * 16 + m0) * 4) * 16384;
  const u16* Bsrc = WoTp + (size_t)((c * 4 + n0) * 4) * 16384;

  f32x4 acc[4][8];
#pragma unroll
  for (int i = 0; i < 4; ++i)
#pragma unroll
    for (int j = 0; j < 8; ++j) acc[i][j] = (f32x4){0.f, 0.f, 0.f, 0.f};

  int aoff[2][4], boff[2][8];
#pragma unroll
  for (int kk = 0; kk < 2; ++kk) {
    const int unit = kk * 4 + l16;
#pragma unroll
    for (int mf = 0; mf < 4; ++mf) {
      const int r = wm * 64 + mf * 16 + l15;
      aoff[kk][mf] = r * 64 + ((unit ^ (r & 7)) << 3);
    }
#pragma unroll
    for (int nf = 0; nf < 8; ++nf) {
      const int r = wn * 128 + nf * 16 + l15;
      boff[kk][nf] = r * 64 + ((unit ^ (r & 7)) << 3);
    }
  }

#define ISSUE(kt, buf)                                                     \
  {                                                                        \
    _Pragma("unroll") for (int i = 0; i < 4; ++i) {                        \
      gll16(Asrc + (size_t)(kt) * 16384 + tid * 8 + i * 4096,              \
            (char*)&As[buf][0] + tid * 16 + i * 8192);                     \
      gll16(Bsrc + (size_t)(kt) * 16384 + tid * 8 + i * 4096,              \
            (char*)&Bs[buf][0] + tid * 16 + i * 8192);                     \
    }                                                                      \
  }

  ISSUE(0, 0);
  ISSUE(1, 1);
  VMCNT(8);   // tile 0 complete
  BARRIER();

#pragma unroll 1
  for (int t = 0; t < 4; ++t) {
    const u16* Ab = As[t & 1];
    const u16* Bb = Bs[t & 1];
#pragma unroll
    for (int kk = 0; kk < 2; ++kk) {
      bf16x8 af[4], bv[8];
#pragma unroll
      for (int mf = 0; mf < 4; ++mf) af[mf] = *reinterpret_cast<const bf16x8*>(Ab + aoff[kk][mf]);
#pragma unroll
      for (int nf = 0; nf < 8; ++nf) bv[nf] = *reinterpret_cast<const bf16x8*>(Bb + boff[kk][nf]);
      __builtin_amdgcn_s_setprio(1);
#pragma unroll
      for (int mf = 0; mf < 4; ++mf)
#pragma unroll
        for (int nf = 0; nf < 8; ++nf)
          acc[mf][nf] = __builtin_amdgcn_mfma_f32_16x16x32_bf16(af[mf], bv[nf], acc[mf][nf], 0, 0, 0);
      __builtin_amdgcn_s_setprio(0);
    }
    if (t == 3) break;
    BARRIER();
    if (t <= 1) {
      ISSUE(t + 2, t & 1);
      VMCNT(8);
    } else {
      VMCNT(0);
    }
    BARRIER();
  }
#undef ISSUE

  const int rbase = m0 * 256;
  const int b = rbase >> 10;
  const int sbase = ((rbase & 1023) << 2) + c;
  float* outp = out + (size_t)(b * SQ + sbase) * DM;
#pragma unroll
  for (int mf = 0; mf < 4; ++mf) {
#pragma unroll
    for (int nf = 0; nf < 8; ++nf) {
      const int gcol = n0 * 256 + wn * 128 + nf * 16 + l15;
      const float bias = bo[gcol];
#pragma unroll
      for (int jj = 0; jj < 4; ++jj) {
        const int rowt = wm * 64 + mf * 16 + l16 * 4 + jj;
        outp[(size_t)rowt * S4 + gcol] = acc[mf][nf][jj] + bias;
      }
    }
  }
}

extern "C" void kernel_launch(void* const* d_in, const int* in_sizes, int n_in,
                              void* d_out, int out_size, void* d_ws, size_t ws_size,
                              hipStream_t stream) {
  const float* x  = (const float*)d_in[0];
  const float* Wq = (const float*)d_in[1];
  const float* bq = (const float*)d_in[2];
  const float* Wk = (const float*)d_in[3];
  const float* bk = (const float*)d_in[4];
  const float* Wv = (const float*)d_in[5];
  const float* bv = (const float*)d_in[6];
  const float* Wo = (const float*)d_in[7];
  const float* bo = (const float*)d_in[8];
  float* out = (float*)d_out;

  char* ws = (char*)d_ws;
  u16*   WTp   = (u16*)(ws);                    // 4*4*16*12288*2 = 6,291,456
  float* biasp = (float*)(ws + 6291456);        // 4*768*4        = 12,288
  u16*   WoTp  = (u16*)(ws + 6303744);          // 4*4*4*16384*2  = 2,097,152
  u16*   QKV   = (u16*)(ws + 8400896);          // 4*4096*768*2   = 25,165,824
  u16*   attnYp= (u16*)(ws + 33566720);         // 4*16*4*16384*2 = 8,388,608

  trans_qkv<<<dim3(16, 12, 4), 256, 0, stream>>>(Wq, Wk, Wv, WTp);
  bias_pack<<<12, 256, 0, stream>>>(bq, bk, bv, biasp);
  trans_wo<<<dim3(4, 16, 4), 256, 0, stream>>>(Wo, WoTp);
  gemm_qkv<<<256, 512, 0, stream>>>(x, WTp, biasp, QKV);
  attn_k<<<256, 256, 0, stream>>>(QKV, attnYp);
  gemm_out<<<256, 512, 0, stream>>>(attnYp, WoTp, bo, out);
}

// Round 5
// 102.868 us; speedup vs baseline: 1.2622x; 1.2622x over previous
//
#include <hip/hip_runtime.h>
#include <hip/hip_bf16.h>

typedef unsigned short u16;
typedef unsigned int u32;
typedef __attribute__((ext_vector_type(8))) __bf16 bf16x8;
typedef __attribute__((ext_vector_type(4))) float f32x4;

#define NB 4       // batch
#define SQ 4096    // seq len
#define DM 1024    // d_model
#define RPC 4096   // rows per residue class (NB*SQ/4)
#define S4 (4 * DM)

#define VMCNT(n) asm volatile("s_waitcnt vmcnt(" #n ")" ::: "memory")
#define BARRIER() asm volatile("s_barrier" ::: "memory")

__device__ __forceinline__ u16 f2b(float f) {
  u32 u = __builtin_bit_cast(u32, f);
  u32 r = u + 0x7fffu + ((u >> 16) & 1u);
  return (u16)(r >> 16);
}
__device__ __forceinline__ u32 cvt2(float lo, float hi) {
  u16 a = __builtin_bit_cast(u16, __float2bfloat16(lo));
  u16 b = __builtin_bit_cast(u16, __float2bfloat16(hi));
  return (u32)a | ((u32)b << 16);
}
__device__ __forceinline__ float dot2(u32 q, u32 k) {
  float ql = __builtin_bit_cast(float, q << 16);
  float qh = __builtin_bit_cast(float, q & 0xffff0000u);
  float kl = __builtin_bit_cast(float, k << 16);
  float kh = __builtin_bit_cast(float, k & 0xffff0000u);
  return ql * kl + qh * kh;
}
__device__ __forceinline__ u32 mul2(u32 v, float p) {
  float lo = __builtin_bit_cast(float, v << 16) * p;
  float hi = __builtin_bit_cast(float, v & 0xffff0000u) * p;
  return (u32)f2b(lo) | ((u32)f2b(hi) << 16);
}
__device__ __forceinline__ void gll16(const void* g, void* l) {
  __builtin_amdgcn_global_load_lds(
      (const __attribute__((address_space(1))) void*)g,
      (__attribute__((address_space(3))) void*)l, 16, 0, 0);
}

// ---- pack x into per-class swizzled bf16 A-tile images ----
// xbT[((c*16+m0)*16 + k64)*16384 + row*64 + ((u^(row&7))<<3) + e]
__global__ __launch_bounds__(256) void pack_x(const float* __restrict__ x,
                                              u16* __restrict__ xbT) {
  const int k64 = blockIdx.x;  // 16
  const int m0 = blockIdx.y;   // 16
  const int c = blockIdx.z;    // 4
  const int tid = threadIdx.x;
  const int b = m0 >> 2;
  const int s0 = (m0 & 3) * 256;
  const int rt = tid >> 2;   // base row 0..63
  const int q4 = tid & 3;    // col quarter (16 floats)
  u16* dst = xbT + ((size_t)((c * 16 + m0) * 16 + k64)) * 16384;
  const float* src =
      x + ((size_t)(b * SQ + (s0 + rt) * 4 + c)) * DM + k64 * 64 + q4 * 16;
#pragma unroll
  for (int j = 0; j < 4; ++j) {
    const int r = rt + j * 64;
    const float* s = src + (size_t)j * 64 * S4;
    float4 v0 = *reinterpret_cast<const float4*>(s);
    float4 v1 = *reinterpret_cast<const float4*>(s + 4);
    float4 v2 = *reinterpret_cast<const float4*>(s + 8);
    float4 v3 = *reinterpret_cast<const float4*>(s + 12);
    uint4 pk0, pk1;
    pk0.x = cvt2(v0.x, v0.y); pk0.y = cvt2(v0.z, v0.w);
    pk0.z = cvt2(v1.x, v1.y); pk0.w = cvt2(v1.z, v1.w);
    pk1.x = cvt2(v2.x, v2.y); pk1.y = cvt2(v2.z, v2.w);
    pk1.z = cvt2(v3.x, v3.y); pk1.w = cvt2(v3.z, v3.w);
    const int u0 = q4 * 2;
    *reinterpret_cast<uint4*>(dst + r * 64 + ((u0 ^ (r & 7)) << 3)) = pk0;
    *reinterpret_cast<uint4*>(dst + r * 64 + (((u0 + 1) ^ (r & 7)) << 3)) = pk1;
  }
}

// ---- pack W{q,k,v} for class c into swizzled LDS-image tiles ----
// B^T panel per class: [768 N][1024 K]; tiles BN=192 x BK=64.
__global__ __launch_bounds__(256) void trans_qkv(const float* __restrict__ Wq,
                                                 const float* __restrict__ Wk,
                                                 const float* __restrict__ Wv,
                                                 u16* __restrict__ WTp) {
  __shared__ float T[64][65];
  const int k0 = blockIdx.x * 64, j0 = blockIdx.y * 64, c = blockIdx.z;
  const int msel = j0 >> 8;
  const float* W = (msel == 0) ? Wq : ((msel == 1) ? Wk : Wv);
  const int slot = (j0 & 255) >> 6;
  const int colbase = (c + 4 * slot) * 64;
  const int tid = threadIdx.x;
  const int rr = tid >> 6, cc = tid & 63;
#pragma unroll
  for (int it = 0; it < 16; ++it) {
    const int kk = rr + it * 4;
    T[kk][cc] = W[(size_t)(k0 + kk) * 1024 + colbase + cc];
  }
  __syncthreads();
  const int k64 = k0 >> 6;
  const int u = cc >> 3, e = cc & 7;
#pragma unroll
  for (int it = 0; it < 16; ++it) {
    const int jj = rr + it * 4;
    const int j = j0 + jj;
    const int n0 = j / 192, nrow = j - n0 * 192;
    WTp[((size_t)((c * 4 + n0) * 16 + k64)) * 12288 + nrow * 64 + (((u ^ (nrow & 7))) << 3) + e] =
        f2b(T[cc][jj]);
  }
}

// ---- pack Wo for class c: B^T [1024 N][256 K], tiles BN=256 x BK=64 ----
__global__ __launch_bounds__(256) void trans_wo(const float* __restrict__ Wo,
                                                u16* __restrict__ WoTp) {
  __shared__ float T[64][65];
  const int j0 = blockIdx.x * 64, e0 = blockIdx.y * 64, c = blockIdx.z;
  const int rowbase = c * 64 + (j0 >> 6) * 256;
  const int tid = threadIdx.x;
  const int rr = tid >> 6, cc = tid & 63;
#pragma unroll
  for (int it = 0; it < 16; ++it) {
    const int jj = rr + it * 4;
    T[jj][cc] = Wo[(size_t)(rowbase + jj) * 1024 + e0 + cc];
  }
  __syncthreads();
  const int k64 = j0 >> 6;
  const int u = cc >> 3, e = cc & 7;
#pragma unroll
  for (int it = 0; it < 16; ++it) {
    const int ee = rr + it * 4;
    const int n = e0 + ee;
    const int n0 = n >> 8, nrow = n & 255;
    WoTp[((size_t)((c * 4 + n0) * 4 + k64)) * 16384 + nrow * 64 + (((u ^ (nrow & 7))) << 3) + e] =
        f2b(T[cc][ee]);
  }
}

__global__ __launch_bounds__(256) void bias_pack(const float* __restrict__ bq,
                                                 const float* __restrict__ bk,
                                                 const float* __restrict__ bv,
                                                 float* __restrict__ biasp) {
  const int idx = blockIdx.x * 256 + threadIdx.x;  // 4*768
  if (idx >= 3072) return;
  const int c = idx / 768, j = idx % 768;
  const int msel = j >> 8, jj = j & 255;
  const int col = (c + 4 * (jj >> 6)) * 64 + (jj & 63);
  const float* bb = (msel == 0) ? bq : ((msel == 1) ? bk : bv);
  biasp[idx] = bb[col];
}

// ---- GEMM1: per class, [4096 x 768] = xb(c)[4096 x 1024] @ WTp^T ----
// BM=256, BN=192, BK=64; 8 waves (4Mx2N), wave tile 64x96.
// Both operands via global_load_lds from pre-swizzled images.
// A triple-buffered (3 tiles ahead), B double-buffered (2 ahead).
__global__ __launch_bounds__(512, 1) void gemm_qkv(const u16* __restrict__ xbT,
                                                   const u16* __restrict__ WTp,
                                                   const float* __restrict__ biasp,
                                                   u16* __restrict__ QKV) {
  __shared__ __align__(16) u16 As3[3 * 16384];  // 3 x (256x64) swizzled
  __shared__ __align__(16) u16 Bs2[2 * 12288];  // 2 x (192x64) swizzled
  const int p = blockIdx.x;
  const int L = (p & 7) * 32 + (p >> 3);  // XCD-contiguous logical id
  const int c = L >> 6, rem = L & 63;
  const int m0 = rem >> 2, n0 = rem & 3;
  const int tid = threadIdx.x;
  const int lane = tid & 63, w = tid >> 6;
  const int wm = w >> 1, wn = w & 1;
  const int l15 = lane & 15, l16 = lane >> 4;

  const u16* Asrc = xbT + (size_t)((c * 16 + m0) * 16) * 16384;
  const u16* Bsrc = WTp + (size_t)((c * 4 + n0) * 16) * 12288;

  f32x4 acc[4][6];
#pragma unroll
  for (int i = 0; i < 4; ++i)
#pragma unroll
    for (int j = 0; j < 6; ++j) acc[i][j] = (f32x4){0.f, 0.f, 0.f, 0.f};

  int abase[2], bbase[2];
#pragma unroll
  for (int kk = 0; kk < 2; ++kk) {
    const int unit = kk * 4 + l16;
    abase[kk] = (wm * 64 + l15) * 64 + ((unit ^ (l15 & 7)) << 3);
    bbase[kk] = (wn * 96 + l15) * 64 + ((unit ^ (l15 & 7)) << 3);
  }

#define ISSUE_A(kt, buf)                                                   \
  {                                                                        \
    _Pragma("unroll") for (int i = 0; i < 4; ++i)                          \
        gll16(Asrc + (size_t)(kt) * 16384 + tid * 8 + i * 4096,            \
              (char*)As3 + (buf) * 32768 + tid * 16 + i * 8192);           \
  }
#define ISSUE_B(kt, buf)                                                   \
  {                                                                        \
    _Pragma("unroll") for (int i = 0; i < 3; ++i)                          \
        gll16(Bsrc + (size_t)(kt) * 12288 + tid * 8 + i * 4096,            \
              (char*)Bs2 + (buf) * 24576 + tid * 16 + i * 8192);           \
  }

  // ---- prologue: A(0..2), B(0..1) in flight ----
  ISSUE_A(0, 0);
  ISSUE_B(0, 0);
  ISSUE_A(1, 1);
  ISSUE_B(1, 1);
  ISSUE_A(2, 2);
  VMCNT(11);  // A(0),B(0) complete
  BARRIER();

  int abuf = 0, bbuf = 0;
#pragma unroll 1
  for (int t = 0; t < 16; ++t) {
    const u16* Ab = As3 + abuf * 16384;
    const u16* Bb = Bs2 + bbuf * 12288;
#pragma unroll
    for (int kk = 0; kk < 2; ++kk) {
      bf16x8 af[4], bv[6];
#pragma unroll
      for (int mf = 0; mf < 4; ++mf)
        af[mf] = *reinterpret_cast<const bf16x8*>(Ab + abase[kk] + mf * 1024);
#pragma unroll
      for (int nf = 0; nf < 6; ++nf)
        bv[nf] = *reinterpret_cast<const bf16x8*>(Bb + bbase[kk] + nf * 1024);
      __builtin_amdgcn_s_setprio(1);
#pragma unroll
      for (int mf = 0; mf < 4; ++mf)
#pragma unroll
        for (int nf = 0; nf < 6; ++nf)
          acc[mf][nf] = __builtin_amdgcn_mfma_f32_16x16x32_bf16(af[mf], bv[nf], acc[mf][nf], 0, 0, 0);
      __builtin_amdgcn_s_setprio(0);
    }
    if (t == 15) break;
    BARRIER();  // all waves done reading bufs abuf/bbuf
    if (t <= 12) ISSUE_A(t + 3, abuf);  // refill just-consumed A buf
    if (t <= 13) ISSUE_B(t + 2, bbuf);  // refill just-consumed B buf
    if (t <= 12) { VMCNT(7); }          // A(t+1),B(t+1) complete
    else if (t == 13) { VMCNT(3); }
    else { VMCNT(0); }
    BARRIER();
    abuf = (abuf == 2) ? 0 : abuf + 1;
    bbuf ^= 1;
  }
#undef ISSUE_A
#undef ISSUE_B

  // ---- epilogue: bias + bf16 store ----
  const int rbase = m0 * 256;
  u16* outc = QKV + (size_t)c * RPC * 768;
#pragma unroll
  for (int mf = 0; mf < 4; ++mf) {
#pragma unroll
    for (int nf = 0; nf < 6; ++nf) {
      const int gcol = n0 * 192 + wn * 96 + nf * 16 + l15;
      const float bias = biasp[c * 768 + gcol];
#pragma unroll
      for (int jj = 0; jj < 4; ++jj) {
        const int rowt = wm * 64 + mf * 16 + l16 * 4 + jj;
        outc[(size_t)(rbase + rowt) * 768 + gcol] = f2b(acc[mf][nf][jj] + bias);
      }
    }
  }
}

// ---- attention: per (c,b,segment,half): diagonal scores + softmax + p*V ----
__global__ __launch_bounds__(256) void attn_k(const u16* __restrict__ QKV,
                                              u16* __restrict__ attnYp) {
  __shared__ float sc[4][128];
  const int blk = blockIdx.x;  // 256
  const int c = blk >> 6, b = (blk >> 4) & 3, n = (blk >> 1) & 7, half = blk & 1;
  const int r0 = b * 1024 + n * 128;
  const int m0 = r0 >> 8;
  const int rb = r0 & 255;
  const u16* base = QKV + ((size_t)c * RPC + r0) * 768;
  const int tid = threadIdx.x;
#pragma unroll
  for (int it = 0; it < 2; ++it) {
    const int tt = tid + it * 256;
    const int t = tt & 127, slot = tt >> 7;
    const u16* q = base + (size_t)t * 768 + slot * 64;
    float s = 0.f;
#pragma unroll
    for (int dd = 0; dd < 8; ++dd) {
      uint4 qa = *reinterpret_cast<const uint4*>(q + dd * 8);
      uint4 ka = *reinterpret_cast<const uint4*>(q + 256 + dd * 8);
      s += dot2(qa.x, ka.x) + dot2(qa.y, ka.y) + dot2(qa.z, ka.z) + dot2(qa.w, ka.w);
    }
    sc[slot][t] = s * 0.125f;
  }
  __syncthreads();
  const int w = tid >> 6, lane = tid & 63;
  float v0 = sc[w][lane], v1 = sc[w][lane + 64];
  float m = fmaxf(v0, v1);
#pragma unroll
  for (int off = 32; off; off >>= 1) m = fmaxf(m, __shfl_xor(m, off));
  float e0 = __expf(v0 - m), e1 = __expf(v1 - m);
  float ssum = e0 + e1;
#pragma unroll
  for (int off = 32; off; off >>= 1) ssum += __shfl_xor(ssum, off);
  const float inv = 1.f / ssum;
  sc[w][lane] = e0 * inv;
  sc[w][lane + 64] = e1 * inv;
  __syncthreads();
  u16* yout = attnYp + (size_t)((c * 16 + m0) * 4) * 16384;
#pragma unroll
  for (int it = 0; it < 8; ++it) {
    const int vi = tid + it * 256;
    const int t = vi >> 4, c8 = (vi & 15) + half * 16;
    const float pr = sc[c8 >> 3][t];
    uint4 va = *reinterpret_cast<const uint4*>(base + (size_t)t * 768 + 512 + c8 * 8);
    uint4 ra;
    ra.x = mul2(va.x, pr); ra.y = mul2(va.y, pr); ra.z = mul2(va.z, pr); ra.w = mul2(va.w, pr);
    const int rloc = rb + t;
    const int k64 = c8 >> 3, uu = c8 & 7, pp = uu ^ (rloc & 7);
    *reinterpret_cast<uint4*>(yout + k64 * 16384 + rloc * 64 + pp * 8) = ra;
  }
}

// ---- GEMM2: per class, out_rows(c)[4096 x 1024] = attnY[4096 x 256] @ Wo ----
__global__ __launch_bounds__(512, 1) void gemm_out(const u16* __restrict__ attnYp,
                                                   const u16* __restrict__ WoTp,
                                                   const float* __restrict__ bo,
                                                   float* __restrict__ out) {
  __shared__ __align__(16) u16 As[2][16384];
  __shared__ __align__(16) u16 Bs[2][16384];
  const int p = blockIdx.x;
  const int L = (p & 7) * 32 + (p >> 3);
  const int c = L >> 6, rem = L & 63;
  const int m0 = rem >> 2, n0 = rem & 3;
  const int tid = threadIdx.x;
  const int lane = tid & 63, w = tid >> 6;
  const int wm = w >> 1, wn = w & 1;
  const int l15 = lane & 15, l16 = lane >> 4;

  const u16* Asrc = attnYp + (size_t)((c * 16 + m0) * 4) * 16384;
  const u16* Bsrc = WoTp + (size_t)((c * 4 + n0) * 4) * 16384;

  f32x4 acc[4][8];
#pragma unroll
  for (int i = 0; i < 4; ++i)
#pragma unroll
    for (int j = 0; j < 8; ++j) acc[i][j] = (f32x4){0.f, 0.f, 0.f, 0.f};

  int aoff[2][4], boff[2][8];
#pragma unroll
  for (int kk = 0; kk < 2; ++kk) {
    const int unit = kk * 4 + l16;
#pragma unroll
    for (int mf = 0; mf < 4; ++mf) {
      const int r = wm * 64 + mf * 16 + l15;
      aoff[kk][mf] = r * 64 + ((unit ^ (r & 7)) << 3);
    }
#pragma unroll
    for (int nf = 0; nf < 8; ++nf) {
      const int r = wn * 128 + nf * 16 + l15;
      boff[kk][nf] = r * 64 + ((unit ^ (r & 7)) << 3);
    }
  }

#define ISSUE(kt, buf)                                                     \
  {                                                                        \
    _Pragma("unroll") for (int i = 0; i < 4; ++i) {                        \
      gll16(Asrc + (size_t)(kt) * 16384 + tid * 8 + i * 4096,              \
            (char*)&As[buf][0] + tid * 16 + i * 8192);                     \
      gll16(Bsrc + (size_t)(kt) * 16384 + tid * 8 + i * 4096,              \
            (char*)&Bs[buf][0] + tid * 16 + i * 8192);                     \
    }                                                                      \
  }

  ISSUE(0, 0);
  ISSUE(1, 1);
  VMCNT(8);   // tile 0 complete
  BARRIER();

#pragma unroll 1
  for (int t = 0; t < 4; ++t) {
    const u16* Ab = As[t & 1];
    const u16* Bb = Bs[t & 1];
#pragma unroll
    for (int kk = 0; kk < 2; ++kk) {
      bf16x8 af[4], bv[8];
#pragma unroll
      for (int mf = 0; mf < 4; ++mf) af[mf] = *reinterpret_cast<const bf16x8*>(Ab + aoff[kk][mf]);
#pragma unroll
      for (int nf = 0; nf < 8; ++nf) bv[nf] = *reinterpret_cast<const bf16x8*>(Bb + boff[kk][nf]);
      __builtin_amdgcn_s_setprio(1);
#pragma unroll
      for (int mf = 0; mf < 4; ++mf)
#pragma unroll
        for (int nf = 0; nf < 8; ++nf)
          acc[mf][nf] = __builtin_amdgcn_mfma_f32_16x16x32_bf16(af[mf], bv[nf], acc[mf][nf], 0, 0, 0);
      __builtin_amdgcn_s_setprio(0);
    }
    if (t == 3) break;
    BARRIER();
    if (t <= 1) {
      ISSUE(t + 2, t & 1);
      VMCNT(8);
    } else {
      VMCNT(0);
    }
    BARRIER();
  }
#undef ISSUE

  const int rbase = m0 * 256;
  const int b = rbase >> 10;
  const int sbase = ((rbase & 1023) << 2) + c;
  float* outp = out + (size_t)(b * SQ + sbase) * DM;
#pragma unroll
  for (int mf = 0; mf < 4; ++mf) {
#pragma unroll
    for (int nf = 0; nf < 8; ++nf) {
      const int gcol = n0 * 256 + wn * 128 + nf * 16 + l15;
      const float bias = bo[gcol];
#pragma unroll
      for (int jj = 0; jj < 4; ++jj) {
        const int rowt = wm * 64 + mf * 16 + l16 * 4 + jj;
        outp[(size_t)rowt * S4 + gcol] = acc[mf][nf][jj] + bias;
      }
    }
  }
}

extern "C" void kernel_launch(void* const* d_in, const int* in_sizes, int n_in,
                              void* d_out, int out_size, void* d_ws, size_t ws_size,
                              hipStream_t stream) {
  const float* x  = (const float*)d_in[0];
  const float* Wq = (const float*)d_in[1];
  const float* bq = (const float*)d_in[2];
  const float* Wk = (const float*)d_in[3];
  const float* bk = (const float*)d_in[4];
  const float* Wv = (const float*)d_in[5];
  const float* bv = (const float*)d_in[6];
  const float* Wo = (const float*)d_in[7];
  const float* bo = (const float*)d_in[8];
  float* out = (float*)d_out;

  // Workspace: xbT 32MB | WoTp 2MB | attnYp 8MB  (total ~42MB)
  char* ws = (char*)d_ws;
  u16* xbT    = (u16*)(ws);                       // 4*16*16*16384*2 = 33,554,432
  u16* WoTp   = (u16*)(ws + 33554432);            // 4*4*4*16384*2   =  2,097,152
  u16* attnYp = (u16*)(ws + 35651584);            // 4*16*4*16384*2  =  8,388,608

  // d_out doubles as scratch until gemm_out overwrites all of it:
  // QKV @0 (25.2MB) | WTp @32MB (6.3MB) | biasp @38MB (12KB)
  char* ob = (char*)d_out;
  u16*   QKV   = (u16*)(ob);                      // 4*4096*768*2 = 25,165,824
  u16*   WTp   = (u16*)(ob + 33554432);           // 6,291,456
  float* biasp = (float*)(ob + 39845888);         // 12,288   (ends 39,858,176 < 64MB)

  pack_x<<<dim3(16, 16, 4), 256, 0, stream>>>(x, xbT);
  trans_qkv<<<dim3(16, 12, 4), 256, 0, stream>>>(Wq, Wk, Wv, WTp);
  bias_pack<<<12, 256, 0, stream>>>(bq, bk, bv, biasp);
  trans_wo<<<dim3(4, 16, 4), 256, 0, stream>>>(Wo, WoTp);
  gemm_qkv<<<256, 512, 0, stream>>>(xbT, WTp, biasp, QKV);
  attn_k<<<256, 256, 0, stream>>>(QKV, attnYp);
  gemm_out<<<256, 512, 0, stream>>>(attnYp, WoTp, bo, out);
}

// Round 6
// 98.011 us; speedup vs baseline: 1.3248x; 1.0496x over previous
//
#include <hip/hip_runtime.h>
#include <hip/hip_bf16.h>

typedef unsigned short u16;
typedef unsigned int u32;
typedef __attribute__((ext_vector_type(8))) __bf16 bf16x8;
typedef __attribute__((ext_vector_type(4))) float f32x4;

#define NB 4       // batch
#define SQ 4096    // seq len
#define DM 1024    // d_model
#define RPC 4096   // rows per residue class (NB*SQ/4)
#define S4 (4 * DM)

#define VMCNT(n) asm volatile("s_waitcnt vmcnt(" #n ")" ::: "memory")
#define BARRIER() asm volatile("s_barrier" ::: "memory")

__device__ __forceinline__ u16 f2b(float f) {
  u32 u = __builtin_bit_cast(u32, f);
  u32 r = u + 0x7fffu + ((u >> 16) & 1u);
  return (u16)(r >> 16);
}
__device__ __forceinline__ u32 cvt2(float lo, float hi) {
  u16 a = __builtin_bit_cast(u16, __float2bfloat16(lo));
  u16 b = __builtin_bit_cast(u16, __float2bfloat16(hi));
  return (u32)a | ((u32)b << 16);
}
__device__ __forceinline__ float dot2(u32 q, u32 k) {
  float ql = __builtin_bit_cast(float, q << 16);
  float qh = __builtin_bit_cast(float, q & 0xffff0000u);
  float kl = __builtin_bit_cast(float, k << 16);
  float kh = __builtin_bit_cast(float, k & 0xffff0000u);
  return ql * kl + qh * kh;
}
__device__ __forceinline__ u32 mul2(u32 v, float p) {
  float lo = __builtin_bit_cast(float, v << 16) * p;
  float hi = __builtin_bit_cast(float, v & 0xffff0000u) * p;
  return (u32)f2b(lo) | ((u32)f2b(hi) << 16);
}
__device__ __forceinline__ void gll16(const void* g, void* l) {
  __builtin_amdgcn_global_load_lds(
      (const __attribute__((address_space(1))) void*)g,
      (__attribute__((address_space(3))) void*)l, 16, 0, 0);
}

// ---- pack x into per-class swizzled bf16 A-tile images (read-coalesced) ----
// Each wave processes one x-row per iteration: lanes read one contiguous 4KB
// row (1KB per load instr); writes scatter to 4x128B image-row segments.
// xbT[((c*16+m0)*16 + k64)*16384 + rloc*64 + ((u^(rloc&7))<<3) + e]
__global__ __launch_bounds__(256) void pack_x(const float* __restrict__ x,
                                              u16* __restrict__ xbT) {
  const int tid = threadIdx.x;
  const int wv = tid >> 6, l = tid & 63;
  const int gr0 = blockIdx.x * 16 + wv * 4;
#pragma unroll
  for (int it = 0; it < 4; ++it) {
    const int gr = gr0 + it;          // global packed row: c*4096 + pr
    const int c = gr >> 12, pr = gr & 4095;
    const int b = pr >> 10;
    const int srow = ((pr & 1023) << 2) + c;
    const int m0 = pr >> 8, rloc = pr & 255;
    const float* src = x + ((size_t)(b * SQ) + srow) * DM;
    u16* dimg = xbT + (size_t)((c * 16 + m0) * 16) * 16384 + rloc * 64;
    const int swzbase = ((((l & 15) >> 1) ^ (rloc & 7)) << 3) + (l & 1) * 4;
#pragma unroll
    for (int i = 0; i < 4; ++i) {
      float4 v = *reinterpret_cast<const float4*>(src + i * 256 + l * 4);
      uint2 pk;
      pk.x = cvt2(v.x, v.y);
      pk.y = cvt2(v.z, v.w);
      const int k64 = i * 4 + (l >> 4);
      *reinterpret_cast<uint2*>(dimg + (size_t)k64 * 16384 + swzbase) = pk;
    }
  }
}

// ---- pack W{q,k,v} for class c into swizzled LDS-image tiles ----
// B^T panel per class: [768 N][1024 K]; tiles BN=192 x BK=64.
__global__ __launch_bounds__(256) void trans_qkv(const float* __restrict__ Wq,
                                                 const float* __restrict__ Wk,
                                                 const float* __restrict__ Wv,
                                                 u16* __restrict__ WTp) {
  __shared__ float T[64][65];
  const int k0 = blockIdx.x * 64, j0 = blockIdx.y * 64, c = blockIdx.z;
  const int msel = j0 >> 8;
  const float* W = (msel == 0) ? Wq : ((msel == 1) ? Wk : Wv);
  const int slot = (j0 & 255) >> 6;
  const int colbase = (c + 4 * slot) * 64;
  const int tid = threadIdx.x;
  const int rr = tid >> 6, cc = tid & 63;
#pragma unroll
  for (int it = 0; it < 16; ++it) {
    const int kk = rr + it * 4;
    T[kk][cc] = W[(size_t)(k0 + kk) * 1024 + colbase + cc];
  }
  __syncthreads();
  const int k64 = k0 >> 6;
  const int u = cc >> 3, e = cc & 7;
#pragma unroll
  for (int it = 0; it < 16; ++it) {
    const int jj = rr + it * 4;
    const int j = j0 + jj;
    const int n0 = j / 192, nrow = j - n0 * 192;
    WTp[((size_t)((c * 4 + n0) * 16 + k64)) * 12288 + nrow * 64 + (((u ^ (nrow & 7))) << 3) + e] =
        f2b(T[cc][jj]);
  }
}

// ---- pack Wo for class c: B^T [1024 N][256 K], tiles BN=256 x BK=64 ----
__global__ __launch_bounds__(256) void trans_wo(const float* __restrict__ Wo,
                                                u16* __restrict__ WoTp) {
  __shared__ float T[64][65];
  const int j0 = blockIdx.x * 64, e0 = blockIdx.y * 64, c = blockIdx.z;
  const int rowbase = c * 64 + (j0 >> 6) * 256;
  const int tid = threadIdx.x;
  const int rr = tid >> 6, cc = tid & 63;
#pragma unroll
  for (int it = 0; it < 16; ++it) {
    const int jj = rr + it * 4;
    T[jj][cc] = Wo[(size_t)(rowbase + jj) * 1024 + e0 + cc];
  }
  __syncthreads();
  const int k64 = j0 >> 6;
  const int u = cc >> 3, e = cc & 7;
#pragma unroll
  for (int it = 0; it < 16; ++it) {
    const int ee = rr + it * 4;
    const int n = e0 + ee;
    const int n0 = n >> 8, nrow = n & 255;
    WoTp[((size_t)((c * 4 + n0) * 4 + k64)) * 16384 + nrow * 64 + (((u ^ (nrow & 7))) << 3) + e] =
        f2b(T[cc][ee]);
  }
}

__global__ __launch_bounds__(256) void bias_pack(const float* __restrict__ bq,
                                                 const float* __restrict__ bk,
                                                 const float* __restrict__ bv,
                                                 float* __restrict__ biasp) {
  const int idx = blockIdx.x * 256 + threadIdx.x;  // 4*768
  if (idx >= 3072) return;
  const int c = idx / 768, j = idx % 768;
  const int msel = j >> 8, jj = j & 255;
  const int col = (c + 4 * (jj >> 6)) * 64 + (jj & 63);
  const float* bb = (msel == 0) ? bq : ((msel == 1) ? bk : bv);
  biasp[idx] = bb[col];
}

// ---- GEMM1: per class, [4096 x 768] = xb(c)[4096 x 1024] @ WTp^T ----
// BM=256, BN=192, BK=64; 8 waves (4Mx2N), wave tile 64x96.
// Both operands via global_load_lds from pre-swizzled images.
// A triple-buffered (3 tiles ahead), B double-buffered (2 ahead).
__global__ __launch_bounds__(512, 1) void gemm_qkv(const u16* __restrict__ xbT,
                                                   const u16* __restrict__ WTp,
                                                   const float* __restrict__ biasp,
                                                   u16* __restrict__ QKV) {
  __shared__ __align__(16) u16 As3[3 * 16384];  // 3 x (256x64) swizzled
  __shared__ __align__(16) u16 Bs2[2 * 12288];  // 2 x (192x64) swizzled
  const int p = blockIdx.x;
  const int L = (p & 7) * 32 + (p >> 3);  // XCD-contiguous logical id
  const int c = L >> 6, rem = L & 63;
  const int m0 = rem >> 2, n0 = rem & 3;
  const int tid = threadIdx.x;
  const int lane = tid & 63, w = tid >> 6;
  const int wm = w >> 1, wn = w & 1;
  const int l15 = lane & 15, l16 = lane >> 4;

  const u16* Asrc = xbT + (size_t)((c * 16 + m0) * 16) * 16384;
  const u16* Bsrc = WTp + (size_t)((c * 4 + n0) * 16) * 12288;

  f32x4 acc[4][6];
#pragma unroll
  for (int i = 0; i < 4; ++i)
#pragma unroll
    for (int j = 0; j < 6; ++j) acc[i][j] = (f32x4){0.f, 0.f, 0.f, 0.f};

  int abase[2], bbase[2];
#pragma unroll
  for (int kk = 0; kk < 2; ++kk) {
    const int unit = kk * 4 + l16;
    abase[kk] = (wm * 64 + l15) * 64 + ((unit ^ (l15 & 7)) << 3);
    bbase[kk] = (wn * 96 + l15) * 64 + ((unit ^ (l15 & 7)) << 3);
  }

#define ISSUE_A(kt, buf)                                                   \
  {                                                                        \
    _Pragma("unroll") for (int i = 0; i < 4; ++i)                          \
        gll16(Asrc + (size_t)(kt) * 16384 + tid * 8 + i * 4096,            \
              (char*)As3 + (buf) * 32768 + tid * 16 + i * 8192);           \
  }
#define ISSUE_B(kt, buf)                                                   \
  {                                                                        \
    _Pragma("unroll") for (int i = 0; i < 3; ++i)                          \
        gll16(Bsrc + (size_t)(kt) * 12288 + tid * 8 + i * 4096,            \
              (char*)Bs2 + (buf) * 24576 + tid * 16 + i * 8192);           \
  }

  // ---- prologue: A(0..2), B(0..1) in flight ----
  ISSUE_A(0, 0);
  ISSUE_B(0, 0);
  ISSUE_A(1, 1);
  ISSUE_B(1, 1);
  ISSUE_A(2, 2);
  VMCNT(11);  // A(0),B(0) complete
  BARRIER();

  int abuf = 0, bbuf = 0;
#pragma unroll 1
  for (int t = 0; t < 16; ++t) {
    const u16* Ab = As3 + abuf * 16384;
    const u16* Bb = Bs2 + bbuf * 12288;
#pragma unroll
    for (int kk = 0; kk < 2; ++kk) {
      bf16x8 af[4], bv[6];
#pragma unroll
      for (int mf = 0; mf < 4; ++mf)
        af[mf] = *reinterpret_cast<const bf16x8*>(Ab + abase[kk] + mf * 1024);
#pragma unroll
      for (int nf = 0; nf < 6; ++nf)
        bv[nf] = *reinterpret_cast<const bf16x8*>(Bb + bbase[kk] + nf * 1024);
      __builtin_amdgcn_s_setprio(1);
#pragma unroll
      for (int mf = 0; mf < 4; ++mf)
#pragma unroll
        for (int nf = 0; nf < 6; ++nf)
          acc[mf][nf] = __builtin_amdgcn_mfma_f32_16x16x32_bf16(af[mf], bv[nf], acc[mf][nf], 0, 0, 0);
      __builtin_amdgcn_s_setprio(0);
    }
    if (t == 15) break;
    BARRIER();  // all waves done reading bufs abuf/bbuf
    if (t <= 12) ISSUE_A(t + 3, abuf);  // refill just-consumed A buf
    if (t <= 13) ISSUE_B(t + 2, bbuf);  // refill just-consumed B buf
    if (t <= 12) { VMCNT(7); }          // A(t+1),B(t+1) complete
    else if (t == 13) { VMCNT(3); }
    else { VMCNT(0); }
    BARRIER();
    abuf = (abuf == 2) ? 0 : abuf + 1;
    bbuf ^= 1;
  }
#undef ISSUE_A
#undef ISSUE_B

  // ---- epilogue: bias + bf16 store ----
  const int rbase = m0 * 256;
  u16* outc = QKV + (size_t)c * RPC * 768;
#pragma unroll
  for (int mf = 0; mf < 4; ++mf) {
#pragma unroll
    for (int nf = 0; nf < 6; ++nf) {
      const int gcol = n0 * 192 + wn * 96 + nf * 16 + l15;
      const float bias = biasp[c * 768 + gcol];
#pragma unroll
      for (int jj = 0; jj < 4; ++jj) {
        const int rowt = wm * 64 + mf * 16 + l16 * 4 + jj;
        outc[(size_t)(rbase + rowt) * 768 + gcol] = f2b(acc[mf][nf][jj] + bias);
      }
    }
  }
}

// ---- attention: per (c,b,segment,half): diagonal scores + softmax + p*V ----
__global__ __launch_bounds__(256) void attn_k(const u16* __restrict__ QKV,
                                              u16* __restrict__ attnYp) {
  __shared__ float sc[4][128];
  const int blk = blockIdx.x;  // 256
  const int c = blk >> 6, b = (blk >> 4) & 3, n = (blk >> 1) & 7, half = blk & 1;
  const int r0 = b * 1024 + n * 128;
  const int m0 = r0 >> 8;
  const int rb = r0 & 255;
  const u16* base = QKV + ((size_t)c * RPC + r0) * 768;
  const int tid = threadIdx.x;
#pragma unroll
  for (int it = 0; it < 2; ++it) {
    const int tt = tid + it * 256;
    const int t = tt & 127, slot = tt >> 7;
    const u16* q = base + (size_t)t * 768 + slot * 64;
    float s = 0.f;
#pragma unroll
    for (int dd = 0; dd < 8; ++dd) {
      uint4 qa = *reinterpret_cast<const uint4*>(q + dd * 8);
      uint4 ka = *reinterpret_cast<const uint4*>(q + 256 + dd * 8);
      s += dot2(qa.x, ka.x) + dot2(qa.y, ka.y) + dot2(qa.z, ka.z) + dot2(qa.w, ka.w);
    }
    sc[slot][t] = s * 0.125f;
  }
  __syncthreads();
  const int w = tid >> 6, lane = tid & 63;
  float v0 = sc[w][lane], v1 = sc[w][lane + 64];
  float m = fmaxf(v0, v1);
#pragma unroll
  for (int off = 32; off; off >>= 1) m = fmaxf(m, __shfl_xor(m, off));
  float e0 = __expf(v0 - m), e1 = __expf(v1 - m);
  float ssum = e0 + e1;
#pragma unroll
  for (int off = 32; off; off >>= 1) ssum += __shfl_xor(ssum, off);
  const float inv = 1.f / ssum;
  sc[w][lane] = e0 * inv;
  sc[w][lane + 64] = e1 * inv;
  __syncthreads();
  u16* yout = attnYp + (size_t)((c * 16 + m0) * 4) * 16384;
#pragma unroll
  for (int it = 0; it < 8; ++it) {
    const int vi = tid + it * 256;
    const int t = vi >> 4, c8 = (vi & 15) + half * 16;
    const float pr = sc[c8 >> 3][t];
    uint4 va = *reinterpret_cast<const uint4*>(base + (size_t)t * 768 + 512 + c8 * 8);
    uint4 ra;
    ra.x = mul2(va.x, pr); ra.y = mul2(va.y, pr); ra.z = mul2(va.z, pr); ra.w = mul2(va.w, pr);
    const int rloc = rb + t;
    const int k64 = c8 >> 3, uu = c8 & 7, pp = uu ^ (rloc & 7);
    *reinterpret_cast<uint4*>(yout + k64 * 16384 + rloc * 64 + pp * 8) = ra;
  }
}

// ---- GEMM2: per class, out_rows(c)[4096 x 1024] = attnY[4096 x 256] @ Wo ----
__global__ __launch_bounds__(512, 1) void gemm_out(const u16* __restrict__ attnYp,
                                                   const u16* __restrict__ WoTp,
                                                   const float* __restrict__ bo,
                                                   float* __restrict__ out) {
  __shared__ __align__(16) u16 As[2][16384];
  __shared__ __align__(16) u16 Bs[2][16384];
  const int p = blockIdx.x;
  const int L = (p & 7) * 32 + (p >> 3);
  const int c = L >> 6, rem = L & 63;
  const int m0 = rem >> 2, n0 = rem & 3;
  const int tid = threadIdx.x;
  const int lane = tid & 63, w = tid >> 6;
  const int wm = w >> 1, wn = w & 1;
  const int l15 = lane & 15, l16 = lane >> 4;

  const u16* Asrc = attnYp + (size_t)((c * 16 + m0) * 4) * 16384;
  const u16* Bsrc = WoTp + (size_t)((c * 4 + n0) * 4) * 16384;

  f32x4 acc[4][8];
#pragma unroll
  for (int i = 0; i < 4; ++i)
#pragma unroll
    for (int j = 0; j < 8; ++j) acc[i][j] = (f32x4){0.f, 0.f, 0.f, 0.f};

  int aoff[2][4], boff[2][8];
#pragma unroll
  for (int kk = 0; kk < 2; ++kk) {
    const int unit = kk * 4 + l16;
#pragma unroll
    for (int mf = 0; mf < 4; ++mf) {
      const int r = wm * 64 + mf * 16 + l15;
      aoff[kk][mf] = r * 64 + ((unit ^ (r & 7)) << 3);
    }
#pragma unroll
    for (int nf = 0; nf < 8; ++nf) {
      const int r = wn * 128 + nf * 16 + l15;
      boff[kk][nf] = r * 64 + ((unit ^ (r & 7)) << 3);
    }
  }

#define ISSUE(kt, buf)                                                     \
  {                                                                        \
    _Pragma("unroll") for (int i = 0; i < 4; ++i) {                        \
      gll16(Asrc + (size_t)(kt) * 16384 + tid * 8 + i * 4096,              \
            (char*)&As[buf][0] + tid * 16 + i * 8192);                     \
      gll16(Bsrc + (size_t)(kt) * 16384 + tid * 8 + i * 4096,              \
            (char*)&Bs[buf][0] + tid * 16 + i * 8192);                     \
    }                                                                      \
  }

  ISSUE(0, 0);
  ISSUE(1, 1);
  VMCNT(8);   // tile 0 complete
  BARRIER();

#pragma unroll 1
  for (int t = 0; t < 4; ++t) {
    const u16* Ab = As[t & 1];
    const u16* Bb = Bs[t & 1];
#pragma unroll
    for (int kk = 0; kk < 2; ++kk) {
      bf16x8 af[4], bv[8];
#pragma unroll
      for (int mf = 0; mf < 4; ++mf) af[mf] = *reinterpret_cast<const bf16x8*>(Ab + aoff[kk][mf]);
#pragma unroll
      for (int nf = 0; nf < 8; ++nf) bv[nf] = *reinterpret_cast<const bf16x8*>(Bb + boff[kk][nf]);
      __builtin_amdgcn_s_setprio(1);
#pragma unroll
      for (int mf = 0; mf < 4; ++mf)
#pragma unroll
        for (int nf = 0; nf < 8; ++nf)
          acc[mf][nf] = __builtin_amdgcn_mfma_f32_16x16x32_bf16(af[mf], bv[nf], acc[mf][nf], 0, 0, 0);
      __builtin_amdgcn_s_setprio(0);
    }
    if (t == 3) break;
    BARRIER();
    if (t <= 1) {
      ISSUE(t + 2, t & 1);
      VMCNT(8);
    } else {
      VMCNT(0);
    }
    BARRIER();
  }
#undef ISSUE

  const int rbase = m0 * 256;
  const int b = rbase >> 10;
  const int sbase = ((rbase & 1023) << 2) + c;
  float* outp = out + (size_t)(b * SQ + sbase) * DM;
#pragma unroll
  for (int mf = 0; mf < 4; ++mf) {
#pragma unroll
    for (int nf = 0; nf < 8; ++nf) {
      const int gcol = n0 * 256 + wn * 128 + nf * 16 + l15;
      const float bias = bo[gcol];
#pragma unroll
      for (int jj = 0; jj < 4; ++jj) {
        const int rowt = wm * 64 + mf * 16 + l16 * 4 + jj;
        outp[(size_t)rowt * S4 + gcol] = acc[mf][nf][jj] + bias;
      }
    }
  }
}

extern "C" void kernel_launch(void* const* d_in, const int* in_sizes, int n_in,
                              void* d_out, int out_size, void* d_ws, size_t ws_size,
                              hipStream_t stream) {
  const float* x  = (const float*)d_in[0];
  const float* Wq = (const float*)d_in[1];
  const float* bq = (const float*)d_in[2];
  const float* Wk = (const float*)d_in[3];
  const float* bk = (const float*)d_in[4];
  const float* Wv = (const float*)d_in[5];
  const float* bv = (const float*)d_in[6];
  const float* Wo = (const float*)d_in[7];
  const float* bo = (const float*)d_in[8];
  float* out = (float*)d_out;

  // Workspace: xbT 32MB | WoTp 2MB | attnYp 8MB  (total ~42MB)
  char* ws = (char*)d_ws;
  u16* xbT    = (u16*)(ws);                       // 4*16*16*16384*2 = 33,554,432
  u16* WoTp   = (u16*)(ws + 33554432);            // 4*4*4*16384*2   =  2,097,152
  u16* attnYp = (u16*)(ws + 35651584);            // 4*16*4*16384*2  =  8,388,608

  // d_out doubles as scratch until gemm_out overwrites all of it:
  // QKV @0 (25.2MB) | WTp @32MB (6.3MB) | biasp @38MB (12KB)
  char* ob = (char*)d_out;
  u16*   QKV   = (u16*)(ob);                      // 4*4096*768*2 = 25,165,824
  u16*   WTp   = (u16*)(ob + 33554432);           // 6,291,456
  float* biasp = (float*)(ob + 39845888);         // 12,288   (ends 39,858,176 < 64MB)

  pack_x<<<1024, 256, 0, stream>>>(x, xbT);
  trans_qkv<<<dim3(16, 12, 4), 256, 0, stream>>>(Wq, Wk, Wv, WTp);
  bias_pack<<<12, 256, 0, stream>>>(bq, bk, bv, biasp);
  trans_wo<<<dim3(4, 16, 4), 256, 0, stream>>>(Wo, WoTp);
  gemm_qkv<<<256, 512, 0, stream>>>(xbT, WTp, biasp, QKV);
  attn_k<<<256, 256, 0, stream>>>(QKV, attnYp);
  gemm_out<<<256, 512, 0, stream>>>(attnYp, WoTp, bo, out);
}

// Round 7
// 88.327 us; speedup vs baseline: 1.4700x; 1.1096x over previous
//
#include <hip/hip_runtime.h>
#include <hip/hip_bf16.h>

typedef unsigned short u16;
typedef unsigned int u32;
typedef __attribute__((ext_vector_type(8))) __bf16 bf16x8;
typedef __attribute__((ext_vector_type(4))) float f32x4;

#define NB 4       // batch
#define SQ 4096    // seq len
#define DM 1024    // d_model
#define RPC 4096   // rows per residue class (NB*SQ/4)
#define S4 (4 * DM)

#define VMCNT(n) asm volatile("s_waitcnt vmcnt(" #n ")" ::: "memory")
#define BARRIER() asm volatile("s_barrier" ::: "memory")

__device__ __forceinline__ u16 f2b(float f) {
  u32 u = __builtin_bit_cast(u32, f);
  u32 r = u + 0x7fffu + ((u >> 16) & 1u);
  return (u16)(r >> 16);
}
__device__ __forceinline__ u32 cvt2(float lo, float hi) {
  u16 a = __builtin_bit_cast(u16, __float2bfloat16(lo));
  u16 b = __builtin_bit_cast(u16, __float2bfloat16(hi));
  return (u32)a | ((u32)b << 16);
}
__device__ __forceinline__ float dot2(u32 q, u32 k) {
  float ql = __builtin_bit_cast(float, q << 16);
  float qh = __builtin_bit_cast(float, q & 0xffff0000u);
  float kl = __builtin_bit_cast(float, k << 16);
  float kh = __builtin_bit_cast(float, k & 0xffff0000u);
  return ql * kl + qh * kh;
}
__device__ __forceinline__ u32 mul2(u32 v, float p) {
  float lo = __builtin_bit_cast(float, v << 16) * p;
  float hi = __builtin_bit_cast(float, v & 0xffff0000u) * p;
  return (u32)f2b(lo) | ((u32)f2b(hi) << 16);
}
__device__ __forceinline__ void gll16(const void* g, void* l) {
  __builtin_amdgcn_global_load_lds(
      (const __attribute__((address_space(1))) void*)g,
      (__attribute__((address_space(3))) void*)l, 16, 0, 0);
}

// ---- fused prep: pack_x | trans_qkv | trans_wo | bias_pack ----
// blocks [0,1024): pack_x; [1024,1792): trans_qkv; [1792,2048): trans_wo;
// [2048,2060): bias_pack.
__global__ __launch_bounds__(256) void prep(const float* __restrict__ x,
                                            const float* __restrict__ Wq,
                                            const float* __restrict__ Wk,
                                            const float* __restrict__ Wv,
                                            const float* __restrict__ Wo,
                                            const float* __restrict__ bq,
                                            const float* __restrict__ bk,
                                            const float* __restrict__ bv,
                                            u16* __restrict__ xbT,
                                            u16* __restrict__ WTp,
                                            u16* __restrict__ WoTp,
                                            float* __restrict__ biasp) {
  __shared__ float T[64][65];
  const int bid = blockIdx.x;
  const int tid = threadIdx.x;
  if (bid < 1024) {
    // ---- pack_x: x -> per-class swizzled bf16 A-tile images ----
    const int wv = tid >> 6, l = tid & 63;
    const int gr0 = bid * 16 + wv * 4;
#pragma unroll
    for (int it = 0; it < 4; ++it) {
      const int gr = gr0 + it;
      const int c = gr >> 12, pr = gr & 4095;
      const int b = pr >> 10;
      const int srow = ((pr & 1023) << 2) + c;
      const int m0 = pr >> 8, rloc = pr & 255;
      const float* src = x + ((size_t)(b * SQ) + srow) * DM;
      u16* dimg = xbT + (size_t)((c * 16 + m0) * 16) * 16384 + rloc * 64;
      const int swzbase = ((((l & 15) >> 1) ^ (rloc & 7)) << 3) + (l & 1) * 4;
#pragma unroll
      for (int i = 0; i < 4; ++i) {
        float4 v = *reinterpret_cast<const float4*>(src + i * 256 + l * 4);
        uint2 pk;
        pk.x = cvt2(v.x, v.y);
        pk.y = cvt2(v.z, v.w);
        const int k64 = i * 4 + (l >> 4);
        *reinterpret_cast<uint2*>(dimg + (size_t)k64 * 16384 + swzbase) = pk;
      }
    }
  } else if (bid < 1792) {
    // ---- trans_qkv: W{q,k,v} -> swizzled B^T tiles [768 N][1024 K], BN=192 ----
    const int q = bid - 1024;           // 0..767 = c*192 + j0blk*16 + k0blk
    const int c = q / 192;
    const int rem = q - c * 192;
    const int j0 = (rem >> 4) * 64;     // 12 values
    const int k0 = (rem & 15) * 64;     // 16 values
    const int msel = j0 >> 8;
    const float* W = (msel == 0) ? Wq : ((msel == 1) ? Wk : Wv);
    const int slot = (j0 & 255) >> 6;
    const int colbase = (c + 4 * slot) * 64;
    const int rr = tid >> 6, cc = tid & 63;
#pragma unroll
    for (int it = 0; it < 16; ++it) {
      const int kk = rr + it * 4;
      T[kk][cc] = W[(size_t)(k0 + kk) * 1024 + colbase + cc];
    }
    __syncthreads();
    const int k64 = k0 >> 6;
    const int u = cc >> 3, e = cc & 7;
#pragma unroll
    for (int it = 0; it < 16; ++it) {
      const int jj = rr + it * 4;
      const int j = j0 + jj;
      const int n0 = j / 192, nrow = j - n0 * 192;
      WTp[((size_t)((c * 4 + n0) * 16 + k64)) * 12288 + nrow * 64 + (((u ^ (nrow & 7))) << 3) + e] =
          f2b(T[cc][jj]);
    }
  } else if (bid < 2048) {
    // ---- trans_wo: Wo -> swizzled B^T tiles [1024 N][256 K], BN=256 ----
    const int q = bid - 1792;           // 0..255 = c*64 + e0blk*4 + j0blk
    const int c = q >> 6;
    const int rem = q & 63;
    const int e0 = (rem >> 2) * 64;
    const int j0 = (rem & 3) * 64;
    const int rowbase = c * 64 + (j0 >> 6) * 256;
    const int rr = tid >> 6, cc = tid & 63;
#pragma unroll
    for (int it = 0; it < 16; ++it) {
      const int jj = rr + it * 4;
      T[jj][cc] = Wo[(size_t)(rowbase + jj) * 1024 + e0 + cc];
    }
    __syncthreads();
    const int k64 = j0 >> 6;
    const int u = cc >> 3, e = cc & 7;
#pragma unroll
    for (int it = 0; it < 16; ++it) {
      const int ee = rr + it * 4;
      const int n = e0 + ee;
      const int n0 = n >> 8, nrow = n & 255;
      WoTp[((size_t)((c * 4 + n0) * 4 + k64)) * 16384 + nrow * 64 + (((u ^ (nrow & 7))) << 3) + e] =
          f2b(T[cc][ee]);
    }
  } else {
    // ---- bias_pack ----
    const int idx = (bid - 2048) * 256 + tid;  // 4*768
    if (idx < 3072) {
      const int c = idx / 768, j = idx % 768;
      const int msel = j >> 8, jj = j & 255;
      const int col = (c + 4 * (jj >> 6)) * 64 + (jj & 63);
      const float* bb = (msel == 0) ? bq : ((msel == 1) ? bk : bv);
      biasp[idx] = bb[col];
    }
  }
}

// ---- GEMM1: per class, [4096 x 768] = xb(c)[4096 x 1024] @ WTp^T ----
// BM=128, BN=192, BK=64; 4 waves (2Mx2N), wave tile 64x96; 256 threads.
// LDS = 2x16KB (A) + 2x24KB (B) = 80KB -> 2 blocks/CU for stall overlap.
// Both operands via global_load_lds from pre-swizzled images; VMCNT(10) ledger.
__global__ __launch_bounds__(256, 2) void gemm_qkv(const u16* __restrict__ xbT,
                                                   const u16* __restrict__ WTp,
                                                   const float* __restrict__ biasp,
                                                   u16* __restrict__ QKV) {
  __shared__ __align__(16) u16 As2[2 * 8192];   // 2 x (128x64) swizzled
  __shared__ __align__(16) u16 Bs2[2 * 12288];  // 2 x (192x64) swizzled
  const int p = blockIdx.x;
  const int L = (p & 7) * 64 + (p >> 3);  // XCD-contiguous logical id (512 = 8*64)
  const int c = L >> 7, r = L & 127;
  const int m0 = r >> 2, n0 = r & 3;      // m0: 0..31 (128-row blocks), n0: 0..3
  const int tid = threadIdx.x;
  const int lane = tid & 63, w = tid >> 6;
  const int wm = w >> 1, wn = w & 1;
  const int l15 = lane & 15, l16 = lane >> 4;

  const u16* Asrc = xbT + (size_t)((c * 16 + (m0 >> 1)) * 16) * 16384 + (m0 & 1) * 8192;
  const u16* Bsrc = WTp + (size_t)((c * 4 + n0) * 16) * 12288;

  f32x4 acc[4][6];
#pragma unroll
  for (int i = 0; i < 4; ++i)
#pragma unroll
    for (int j = 0; j < 6; ++j) acc[i][j] = (f32x4){0.f, 0.f, 0.f, 0.f};

  int abase[2], bbase[2];
#pragma unroll
  for (int kk = 0; kk < 2; ++kk) {
    const int unit = kk * 4 + l16;
    abase[kk] = (wm * 64 + l15) * 64 + ((unit ^ (l15 & 7)) << 3);
    bbase[kk] = (wn * 96 + l15) * 64 + ((unit ^ (l15 & 7)) << 3);
  }

#define ISSUE_A(kt, buf)                                                   \
  {                                                                        \
    _Pragma("unroll") for (int i = 0; i < 4; ++i)                          \
        gll16(Asrc + (size_t)(kt) * 16384 + i * 2048 + tid * 8,            \
              (char*)As2 + (buf) * 16384 + i * 4096 + tid * 16);           \
  }
#define ISSUE_B(kt, buf)                                                   \
  {                                                                        \
    _Pragma("unroll") for (int i = 0; i < 6; ++i)                          \
        gll16(Bsrc + (size_t)(kt) * 12288 + i * 2048 + tid * 8,            \
              (char*)Bs2 + (buf) * 24576 + i * 4096 + tid * 16);           \
  }

  // ---- prologue: tiles 0,1 in flight (10 ops each) ----
  ISSUE_A(0, 0);
  ISSUE_B(0, 0);
  ISSUE_A(1, 1);
  ISSUE_B(1, 1);
  VMCNT(10);  // tile 0 complete
  BARRIER();

#pragma unroll 1
  for (int t = 0; t < 16; ++t) {
    const u16* Ab = As2 + (t & 1) * 8192;
    const u16* Bb = Bs2 + (t & 1) * 12288;
#pragma unroll
    for (int kk = 0; kk < 2; ++kk) {
      bf16x8 af[4], bv[6];
#pragma unroll
      for (int mf = 0; mf < 4; ++mf)
        af[mf] = *reinterpret_cast<const bf16x8*>(Ab + abase[kk] + mf * 1024);
#pragma unroll
      for (int nf = 0; nf < 6; ++nf)
        bv[nf] = *reinterpret_cast<const bf16x8*>(Bb + bbase[kk] + nf * 1024);
      __builtin_amdgcn_s_setprio(1);
#pragma unroll
      for (int mf = 0; mf < 4; ++mf)
#pragma unroll
        for (int nf = 0; nf < 6; ++nf)
          acc[mf][nf] = __builtin_amdgcn_mfma_f32_16x16x32_bf16(af[mf], bv[nf], acc[mf][nf], 0, 0, 0);
      __builtin_amdgcn_s_setprio(0);
    }
    if (t == 15) break;
    BARRIER();  // all waves done reading buf t&1
    if (t <= 13) {
      ISSUE_A(t + 2, t & 1);  // refill just-consumed bufs with tile t+2
      ISSUE_B(t + 2, t & 1);
      VMCNT(10);              // tile t+1 complete; t+2 (10 ops) in flight
    } else {
      VMCNT(0);               // t=14: drain tile 15
    }
    BARRIER();
  }
#undef ISSUE_A
#undef ISSUE_B

  // ---- epilogue: bias + bf16 store ----
  const int rbase = m0 * 128;
  u16* outc = QKV + (size_t)c * RPC * 768;
#pragma unroll
  for (int mf = 0; mf < 4; ++mf) {
#pragma unroll
    for (int nf = 0; nf < 6; ++nf) {
      const int gcol = n0 * 192 + wn * 96 + nf * 16 + l15;
      const float bias = biasp[c * 768 + gcol];
#pragma unroll
      for (int jj = 0; jj < 4; ++jj) {
        const int rowt = wm * 64 + mf * 16 + l16 * 4 + jj;
        outc[(size_t)(rbase + rowt) * 768 + gcol] = f2b(acc[mf][nf][jj] + bias);
      }
    }
  }
}

// ---- attention: per (c,b,segment,half): diagonal scores + softmax + p*V ----
__global__ __launch_bounds__(256) void attn_k(const u16* __restrict__ QKV,
                                              u16* __restrict__ attnYp) {
  __shared__ float sc[4][128];
  const int blk = blockIdx.x;  // 256
  const int c = blk >> 6, b = (blk >> 4) & 3, n = (blk >> 1) & 7, half = blk & 1;
  const int r0 = b * 1024 + n * 128;
  const int m0 = r0 >> 8;
  const int rb = r0 & 255;
  const u16* base = QKV + ((size_t)c * RPC + r0) * 768;
  const int tid = threadIdx.x;
#pragma unroll
  for (int it = 0; it < 2; ++it) {
    const int tt = tid + it * 256;
    const int t = tt & 127, slot = tt >> 7;
    const u16* q = base + (size_t)t * 768 + slot * 64;
    float s = 0.f;
#pragma unroll
    for (int dd = 0; dd < 8; ++dd) {
      uint4 qa = *reinterpret_cast<const uint4*>(q + dd * 8);
      uint4 ka = *reinterpret_cast<const uint4*>(q + 256 + dd * 8);
      s += dot2(qa.x, ka.x) + dot2(qa.y, ka.y) + dot2(qa.z, ka.z) + dot2(qa.w, ka.w);
    }
    sc[slot][t] = s * 0.125f;
  }
  __syncthreads();
  const int w = tid >> 6, lane = tid & 63;
  float v0 = sc[w][lane], v1 = sc[w][lane + 64];
  float m = fmaxf(v0, v1);
#pragma unroll
  for (int off = 32; off; off >>= 1) m = fmaxf(m, __shfl_xor(m, off));
  float e0 = __expf(v0 - m), e1 = __expf(v1 - m);
  float ssum = e0 + e1;
#pragma unroll
  for (int off = 32; off; off >>= 1) ssum += __shfl_xor(ssum, off);
  const float inv = 1.f / ssum;
  sc[w][lane] = e0 * inv;
  sc[w][lane + 64] = e1 * inv;
  __syncthreads();
  u16* yout = attnYp + (size_t)((c * 16 + m0) * 4) * 16384;
#pragma unroll
  for (int it = 0; it < 8; ++it) {
    const int vi = tid + it * 256;
    const int t = vi >> 4, c8 = (vi & 15) + half * 16;
    const float pr = sc[c8 >> 3][t];
    uint4 va = *reinterpret_cast<const uint4*>(base + (size_t)t * 768 + 512 + c8 * 8);
    uint4 ra;
    ra.x = mul2(va.x, pr); ra.y = mul2(va.y, pr); ra.z = mul2(va.z, pr); ra.w = mul2(va.w, pr);
    const int rloc = rb + t;
    const int k64 = c8 >> 3, uu = c8 & 7, pp = uu ^ (rloc & 7);
    *reinterpret_cast<uint4*>(yout + k64 * 16384 + rloc * 64 + pp * 8) = ra;
  }
}

// ---- GEMM2: per class, out_rows(c)[4096 x 1024] = attnY[4096 x 256] @ Wo ----
__global__ __launch_bounds__(512, 1) void gemm_out(const u16* __restrict__ attnYp,
                                                   const u16* __restrict__ WoTp,
                                                   const float* __restrict__ bo,
                                                   float* __restrict__ out) {
  __shared__ __align__(16) u16 As[2][16384];
  __shared__ __align__(16) u16 Bs[2][16384];
  const int p = blockIdx.x;
  const int L = (p & 7) * 32 + (p >> 3);
  const int c = L >> 6, rem = L & 63;
  const int m0 = rem >> 2, n0 = rem & 3;
  const int tid = threadIdx.x;
  const int lane = tid & 63, w = tid >> 6;
  const int wm = w >> 1, wn = w & 1;
  const int l15 = lane & 15, l16 = lane >> 4;

  const u16* Asrc = attnYp + (size_t)((c * 16 + m0) * 4) * 16384;
  const u16* Bsrc = WoTp + (size_t)((c * 4 + n0) * 4) * 16384;

  f32x4 acc[4][8];
#pragma unroll
  for (int i = 0; i < 4; ++i)
#pragma unroll
    for (int j = 0; j < 8; ++j) acc[i][j] = (f32x4){0.f, 0.f, 0.f, 0.f};

  int aoff[2][4], boff[2][8];
#pragma unroll
  for (int kk = 0; kk < 2; ++kk) {
    const int unit = kk * 4 + l16;
#pragma unroll
    for (int mf = 0; mf < 4; ++mf) {
      const int r = wm * 64 + mf * 16 + l15;
      aoff[kk][mf] = r * 64 + ((unit ^ (r & 7)) << 3);
    }
#pragma unroll
    for (int nf = 0; nf < 8; ++nf) {
      const int r = wn * 128 + nf * 16 + l15;
      boff[kk][nf] = r * 64 + ((unit ^ (r & 7)) << 3);
    }
  }

#define ISSUE(kt, buf)                                                     \
  {                                                                        \
    _Pragma("unroll") for (int i = 0; i < 4; ++i) {                        \
      gll16(Asrc + (size_t)(kt) * 16384 + tid * 8 + i * 4096,              \
            (char*)&As[buf][0] + tid * 16 + i * 8192);                     \
      gll16(Bsrc + (size_t)(kt) * 16384 + tid * 8 + i * 4096,              \
            (char*)&Bs[buf][0] + tid * 16 + i * 8192);                     \
    }                                                                      \
  }

  ISSUE(0, 0);
  ISSUE(1, 1);
  VMCNT(8);   // tile 0 complete
  BARRIER();

#pragma unroll 1
  for (int t = 0; t < 4; ++t) {
    const u16* Ab = As[t & 1];
    const u16* Bb = Bs[t & 1];
#pragma unroll
    for (int kk = 0; kk < 2; ++kk) {
      bf16x8 af[4], bv[8];
#pragma unroll
      for (int mf = 0; mf < 4; ++mf) af[mf] = *reinterpret_cast<const bf16x8*>(Ab + aoff[kk][mf]);
#pragma unroll
      for (int nf = 0; nf < 8; ++nf) bv[nf] = *reinterpret_cast<const bf16x8*>(Bb + boff[kk][nf]);
      __builtin_amdgcn_s_setprio(1);
#pragma unroll
      for (int mf = 0; mf < 4; ++mf)
#pragma unroll
        for (int nf = 0; nf < 8; ++nf)
          acc[mf][nf] = __builtin_amdgcn_mfma_f32_16x16x32_bf16(af[mf], bv[nf], acc[mf][nf], 0, 0, 0);
      __builtin_amdgcn_s_setprio(0);
    }
    if (t == 3) break;
    BARRIER();
    if (t <= 1) {
      ISSUE(t + 2, t & 1);
      VMCNT(8);
    } else {
      VMCNT(0);
    }
    BARRIER();
  }
#undef ISSUE

  const int rbase = m0 * 256;
  const int b = rbase >> 10;
  const int sbase = ((rbase & 1023) << 2) + c;
  float* outp = out + (size_t)(b * SQ + sbase) * DM;
#pragma unroll
  for (int mf = 0; mf < 4; ++mf) {
#pragma unroll
    for (int nf = 0; nf < 8; ++nf) {
      const int gcol = n0 * 256 + wn * 128 + nf * 16 + l15;
      const float bias = bo[gcol];
#pragma unroll
      for (int jj = 0; jj < 4; ++jj) {
        const int rowt = wm * 64 + mf * 16 + l16 * 4 + jj;
        outp[(size_t)rowt * S4 + gcol] = acc[mf][nf][jj] + bias;
      }
    }
  }
}

extern "C" void kernel_launch(void* const* d_in, const int* in_sizes, int n_in,
                              void* d_out, int out_size, void* d_ws, size_t ws_size,
                              hipStream_t stream) {
  const float* x  = (const float*)d_in[0];
  const float* Wq = (const float*)d_in[1];
  const float* bq = (const float*)d_in[2];
  const float* Wk = (const float*)d_in[3];
  const float* bk = (const float*)d_in[4];
  const float* Wv = (const float*)d_in[5];
  const float* bv = (const float*)d_in[6];
  const float* Wo = (const float*)d_in[7];
  const float* bo = (const float*)d_in[8];
  float* out = (float*)d_out;

  // Workspace: xbT 32MB | WoTp 2MB | attnYp 8MB  (total ~42MB)
  char* ws = (char*)d_ws;
  u16* xbT    = (u16*)(ws);                       // 4*16*16*16384*2 = 33,554,432
  u16* WoTp   = (u16*)(ws + 33554432);            // 4*4*4*16384*2   =  2,097,152
  u16* attnYp = (u16*)(ws + 35651584);            // 4*16*4*16384*2  =  8,388,608

  // d_out doubles as scratch until gemm_out overwrites all of it:
  // QKV @0 (25.2MB) | WTp @32MB (6.3MB) | biasp @38MB (12KB)
  char* ob = (char*)d_out;
  u16*   QKV   = (u16*)(ob);                      // 4*4096*768*2 = 25,165,824
  u16*   WTp   = (u16*)(ob + 33554432);           // 6,291,456
  float* biasp = (float*)(ob + 39845888);         // 12,288   (ends 39,858,176 < 64MB)

  prep<<<2060, 256, 0, stream>>>(x, Wq, Wk, Wv, Wo, bq, bk, bv, xbT, WTp, WoTp, biasp);
  gemm_qkv<<<512, 256, 0, stream>>>(xbT, WTp, biasp, QKV);
  attn_k<<<256, 256, 0, stream>>>(QKV, attnYp);
  gemm_out<<<256, 512, 0, stream>>>(attnYp, WoTp, bo, out);
}